// Round 1
// 255.442 us; speedup vs baseline: 1.0510x; 1.0510x over previous
//
#include <hip/hip_runtime.h>

// VQ nearest-embedding, fused split-fp16 MFMA, double-buffered LDS.
// argmin_k ||x-e_k||^2 == argmin_k (0.5*||e_k||^2 - x.e_k).
// x = xh+xl, e = eh+el (fp16 RNE splits); 3 MFMA terms (hh, hl, lh).
// R6: hoist ALL split16 conversion out of the hot loop.
//   - pack_emb: emb -> ws as d-pair-packed uints (h|h<<16),(l|l<<16); was
//     converted redundantly by all 256 blocks every kt pass.
//   - pack_x:   x -> OUT-as-scratch, same packing, per-bq slab layout.
//     Safe: block (bq,sb) reads only columns [sb,sb+128) of slab bq; gather
//     writes of any other block touch a disjoint column range; same-block
//     read->write ordered by the vmcnt(0) drain at __syncthreads.
//   Hot-loop staging is now pure loads + raw LDS writes (zero convert VALU);
//   LDS bits identical to R5 -> results bit-identical (absmax 0).
// Fallback (ws too small): R5 in-kernel conversion path, template PRE=false.

typedef __attribute__((ext_vector_type(8))) _Float16 half8v;  // 8 fp16 = 4 VGPRs
typedef __attribute__((ext_vector_type(16))) float floatx16;  // 32x32 acc
typedef unsigned int uint;
typedef unsigned short ushort;

#define DD 256
#define KK 2048
#define SS 1024
#define NN 32768
#define MT 128      // latents per block
#define NTT 256     // codes per kt tile (8 tiles cover K=2048)
#define LDA 24      // LDS row stride in fp16 elems (48 B: 16B-aligned, banks spread)
#define MFMA_F16 __builtin_amdgcn_mfma_f32_32x32x16_f16

#define XSLAB  262144   // floats (=uints) per batch slab of x/out: 2 planes * 128 d2 * 1024 s
#define XPLANE 131072   // uints per plane within a slab: 128 d2 * 1024 s
#define EPLANE 262144   // uints per packed-emb plane: 128 d2 * 2048 k

union HU { _Float16 f; ushort u; };

__device__ __forceinline__ void split16(float v, ushort& h, ushort& l) {
    HU a, b;
    a.f = (_Float16)v;                       // RNE
    b.f = (_Float16)(v - (float)a.f);
    h = a.u; l = b.u;
}

__global__ __launch_bounds__(256) void hn_kernel(const float* __restrict__ emb,
                                                 float* __restrict__ hn) {
    int k = blockIdx.x * 256 + threadIdx.x;
    float a = 0.f;
#pragma unroll 32
    for (int d = 0; d < DD; ++d) { float e = emb[d * KK + k]; a += e * e; }
    hn[k] = 0.5f * a;
}

// emb (d,k) f32 -> eh2/el2 (d2,k) uints: h(2*d2)|h(2*d2+1)<<16 etc.
__global__ __launch_bounds__(256) void pack_emb(const float* __restrict__ emb,
                                                uint* __restrict__ epk) {
    int idx = blockIdx.x * 256 + threadIdx.x;     // 262144 = 128 d2 * 2048 k
    int k = idx & (KK - 1);
    int d2 = idx >> 11;
    float a = emb[(size_t)(2 * d2) * KK + k];
    float b = emb[(size_t)(2 * d2 + 1) * KK + k];
    ushort h0, l0, h1, l1;
    split16(a, h0, l0);
    split16(b, h1, l1);
    epk[idx] = (uint)h0 | ((uint)h1 << 16);
    epk[EPLANE + idx] = (uint)l0 | ((uint)l1 << 16);
}

// x (bq,d,s) f32 -> out-as-scratch slabs: [bq][plane][d2][s] packed uints.
__global__ __launch_bounds__(256) void pack_x(const float* __restrict__ x,
                                              uint* __restrict__ px) {
    int idx = blockIdx.x * 256 + threadIdx.x;     // 1048576 = 32 bq * 128 d2 * 256 s4
    int s4 = idx & 255;
    int d2 = (idx >> 8) & 127;
    int bq = idx >> 15;
    const float4* xp = reinterpret_cast<const float4*>(
        x + ((size_t)(bq * DD + 2 * d2)) * SS) + s4;
    float4 a = xp[0];
    float4 b = xp[SS / 4];                        // next d row
    ushort h0, l0, h1, l1;
    uint4 th, tl;
    split16(a.x, h0, l0); split16(b.x, h1, l1);
    th.x = (uint)h0 | ((uint)h1 << 16); tl.x = (uint)l0 | ((uint)l1 << 16);
    split16(a.y, h0, l0); split16(b.y, h1, l1);
    th.y = (uint)h0 | ((uint)h1 << 16); tl.y = (uint)l0 | ((uint)l1 << 16);
    split16(a.z, h0, l0); split16(b.z, h1, l1);
    th.z = (uint)h0 | ((uint)h1 << 16); tl.z = (uint)l0 | ((uint)l1 << 16);
    split16(a.w, h0, l0); split16(b.w, h1, l1);
    th.w = (uint)h0 | ((uint)h1 << 16); tl.w = (uint)l0 | ((uint)l1 << 16);
    size_t o4 = (size_t)bq * (XSLAB / 4) + (size_t)d2 * (SS / 4) + s4;
    reinterpret_cast<uint4*>(px)[o4] = th;
    reinterpret_cast<uint4*>(px)[o4 + XPLANE / 4] = tl;
}

template <bool PRE>
__global__ __launch_bounds__(512, 1) void vq_fused(
        const float* __restrict__ x, const float* __restrict__ emb,
        const float* __restrict__ hn, const uint* __restrict__ epk,
        float* out) {
    __shared__ ushort Ah[2][MT * LDA], Al[2][MT * LDA];     // 6 KB each plane/buf
    __shared__ ushort Bh[2][NTT * LDA], Bl[2][NTT * LDA];   // 12 KB each plane/buf
    __shared__ float sv[4][MT];
    __shared__ int   sc[4][MT];
    __shared__ int   bc[MT];

    const int tid = threadIdx.x;
    const int lane = tid & 63;
    const int wid = tid >> 6;          // 8 waves: 2(m) x 4(n)
    const int colk = lane & 31;
    const int half = lane >> 5;
    const int wm = (wid & 1) * 64;
    const int wn = (wid >> 1) * 64;

    const int base_n = blockIdx.x * MT;
    const int bq = base_n >> 10;          // batch (SS = 1024)
    const int sb = base_n & (SS - 1);     // spatial base

    // staging assignment (512 threads)
    const int lat_a = tid & 127;          // A: one latent, 4 d's
    const int dqa = (tid >> 7) * 4;
    const int cod_b = tid & 255;          // B: one code, 8 d's
    const int dqb = (tid >> 8) * 8;

    // fallback-path global bases
    const float* xb = x + ((size_t)bq * DD + dqa) * SS + sb + lat_a;
    // PRE-path global bases (packed)
    const uint* aH = reinterpret_cast<const uint*>(out)
                     + (size_t)bq * XSLAB + (size_t)(dqa >> 1) * SS + sb + lat_a;
    const uint* eH = epk + (size_t)(dqb >> 1) * KK + cod_b;

    floatx16 acc[2][2];
#pragma unroll
    for (int i = 0; i < 2; ++i)
#pragma unroll
        for (int j = 0; j < 2; ++j) acc[i][j] = (floatx16)(0.0f);

    float bestv[2][16];
    int bestc[2][16];
#pragma unroll
    for (int t = 0; t < 2; ++t)
#pragma unroll
        for (int r = 0; r < 16; ++r) { bestv[t][r] = 3.4e38f; bestc[t][r] = 0; }

    float fa[4], fb[8];
    uint ua[4], ub[8];
    // ---- prefetch chunk 0 (kt=0, dt=0) ----
    if constexpr (PRE) {
#pragma unroll
        for (int i = 0; i < 2; ++i) {
            ua[i] = aH[(size_t)i * SS];
            ua[2 + i] = aH[XPLANE + (size_t)i * SS];
        }
#pragma unroll
        for (int i = 0; i < 4; ++i) {
            ub[i] = eH[(size_t)i * KK];
            ub[4 + i] = eH[EPLANE + (size_t)i * KK];
        }
    } else {
#pragma unroll
        for (int i = 0; i < 4; ++i) fa[i] = xb[(size_t)i * SS];
        const float* p = emb + (size_t)dqb * KK + cod_b;
#pragma unroll
        for (int i = 0; i < 8; ++i) fb[i] = p[(size_t)i * KK];
    }
    // ---- stage chunk 0 -> buffer 0 ----
    if constexpr (PRE) {
        uint2 w; uint4 t;
        w.x = ua[0]; w.y = ua[1];
        *reinterpret_cast<uint2*>(&Ah[0][lat_a * LDA + dqa]) = w;
        w.x = ua[2]; w.y = ua[3];
        *reinterpret_cast<uint2*>(&Al[0][lat_a * LDA + dqa]) = w;
        t.x = ub[0]; t.y = ub[1]; t.z = ub[2]; t.w = ub[3];
        *reinterpret_cast<uint4*>(&Bh[0][cod_b * LDA + dqb]) = t;
        t.x = ub[4]; t.y = ub[5]; t.z = ub[6]; t.w = ub[7];
        *reinterpret_cast<uint4*>(&Bl[0][cod_b * LDA + dqb]) = t;
    } else {
        ushort h[8], l[8];
#pragma unroll
        for (int i = 0; i < 4; ++i) split16(fa[i], h[i], l[i]);
        uint2 w;
        w.x = (uint)h[0] | ((uint)h[1] << 16);
        w.y = (uint)h[2] | ((uint)h[3] << 16);
        *reinterpret_cast<uint2*>(&Ah[0][lat_a * LDA + dqa]) = w;
        w.x = (uint)l[0] | ((uint)l[1] << 16);
        w.y = (uint)l[2] | ((uint)l[3] << 16);
        *reinterpret_cast<uint2*>(&Al[0][lat_a * LDA + dqa]) = w;
#pragma unroll
        for (int i = 0; i < 8; ++i) split16(fb[i], h[i], l[i]);
        uint4 t;
        t.x = (uint)h[0] | ((uint)h[1] << 16);
        t.y = (uint)h[2] | ((uint)h[3] << 16);
        t.z = (uint)h[4] | ((uint)h[5] << 16);
        t.w = (uint)h[6] | ((uint)h[7] << 16);
        *reinterpret_cast<uint4*>(&Bh[0][cod_b * LDA + dqb]) = t;
        t.x = (uint)l[0] | ((uint)l[1] << 16);
        t.y = (uint)l[2] | ((uint)l[3] << 16);
        t.z = (uint)l[4] | ((uint)l[5] << 16);
        t.w = (uint)l[6] | ((uint)l[7] << 16);
        *reinterpret_cast<uint4*>(&Bl[0][cod_b * LDA + dqb]) = t;
    }
    __syncthreads();

    for (int c = 0; c < 128; ++c) {          // 8 kt x 16 dt chunks of K-depth 16
        const int cur = c & 1, nxt = cur ^ 1;
        // ---- prefetch next chunk's globals (in flight during MFMA) ----
        if (c < 127) {
            const int c1 = c + 1;
            const int kt1 = c1 >> 4;
            const int dt1 = (c1 & 15) * 16;
            if constexpr (PRE) {
                const uint* pa = aH + (size_t)(dt1 >> 1) * SS;
#pragma unroll
                for (int i = 0; i < 2; ++i) {
                    ua[i] = pa[(size_t)i * SS];
                    ua[2 + i] = pa[XPLANE + (size_t)i * SS];
                }
                const uint* pb = eH + (size_t)(dt1 >> 1) * KK + kt1 * NTT;
#pragma unroll
                for (int i = 0; i < 4; ++i) {
                    ub[i] = pb[(size_t)i * KK];
                    ub[4 + i] = pb[EPLANE + (size_t)i * KK];
                }
            } else {
#pragma unroll
                for (int i = 0; i < 4; ++i) fa[i] = xb[(size_t)(dt1 + i) * SS];
                const float* p = emb + (size_t)(dt1 + dqb) * KK + kt1 * NTT + cod_b;
#pragma unroll
                for (int i = 0; i < 8; ++i) fb[i] = p[(size_t)i * KK];
            }
        }
        // ---- fragments from current buffer + 12 MFMA (3 terms x 2x2) ----
        const int fo = colk * LDA + half * 8;
        half8v ah0 = *reinterpret_cast<const half8v*>(&Ah[cur][fo + wm * LDA]);
        half8v ah1 = *reinterpret_cast<const half8v*>(&Ah[cur][fo + (wm + 32) * LDA]);
        half8v al0 = *reinterpret_cast<const half8v*>(&Al[cur][fo + wm * LDA]);
        half8v al1 = *reinterpret_cast<const half8v*>(&Al[cur][fo + (wm + 32) * LDA]);
        half8v bh0 = *reinterpret_cast<const half8v*>(&Bh[cur][fo + wn * LDA]);
        half8v bh1 = *reinterpret_cast<const half8v*>(&Bh[cur][fo + (wn + 32) * LDA]);
        half8v bl0 = *reinterpret_cast<const half8v*>(&Bl[cur][fo + wn * LDA]);
        half8v bl1 = *reinterpret_cast<const half8v*>(&Bl[cur][fo + (wn + 32) * LDA]);

        acc[0][0] = MFMA_F16(ah0, bh0, acc[0][0], 0, 0, 0);
        acc[0][0] = MFMA_F16(ah0, bl0, acc[0][0], 0, 0, 0);
        acc[0][0] = MFMA_F16(al0, bh0, acc[0][0], 0, 0, 0);

        acc[0][1] = MFMA_F16(ah0, bh1, acc[0][1], 0, 0, 0);
        acc[0][1] = MFMA_F16(ah0, bl1, acc[0][1], 0, 0, 0);
        acc[0][1] = MFMA_F16(al0, bh1, acc[0][1], 0, 0, 0);

        acc[1][0] = MFMA_F16(ah1, bh0, acc[1][0], 0, 0, 0);
        acc[1][0] = MFMA_F16(ah1, bl0, acc[1][0], 0, 0, 0);
        acc[1][0] = MFMA_F16(al1, bh0, acc[1][0], 0, 0, 0);

        acc[1][1] = MFMA_F16(ah1, bh1, acc[1][1], 0, 0, 0);
        acc[1][1] = MFMA_F16(ah1, bl1, acc[1][1], 0, 0, 0);
        acc[1][1] = MFMA_F16(al1, bh1, acc[1][1], 0, 0, 0);

        // ---- stage prefetched -> NEXT buffer (overlaps MFMA) ----
        if (c < 127) {
            if constexpr (PRE) {
                uint2 w; uint4 t;
                w.x = ua[0]; w.y = ua[1];
                *reinterpret_cast<uint2*>(&Ah[nxt][lat_a * LDA + dqa]) = w;
                w.x = ua[2]; w.y = ua[3];
                *reinterpret_cast<uint2*>(&Al[nxt][lat_a * LDA + dqa]) = w;
                t.x = ub[0]; t.y = ub[1]; t.z = ub[2]; t.w = ub[3];
                *reinterpret_cast<uint4*>(&Bh[nxt][cod_b * LDA + dqb]) = t;
                t.x = ub[4]; t.y = ub[5]; t.z = ub[6]; t.w = ub[7];
                *reinterpret_cast<uint4*>(&Bl[nxt][cod_b * LDA + dqb]) = t;
            } else {
                ushort h[8], l[8];
#pragma unroll
                for (int i = 0; i < 4; ++i) split16(fa[i], h[i], l[i]);
                uint2 w;
                w.x = (uint)h[0] | ((uint)h[1] << 16);
                w.y = (uint)h[2] | ((uint)h[3] << 16);
                *reinterpret_cast<uint2*>(&Ah[nxt][lat_a * LDA + dqa]) = w;
                w.x = (uint)l[0] | ((uint)l[1] << 16);
                w.y = (uint)l[2] | ((uint)l[3] << 16);
                *reinterpret_cast<uint2*>(&Al[nxt][lat_a * LDA + dqa]) = w;
#pragma unroll
                for (int i = 0; i < 8; ++i) split16(fb[i], h[i], l[i]);
                uint4 t;
                t.x = (uint)h[0] | ((uint)h[1] << 16);
                t.y = (uint)h[2] | ((uint)h[3] << 16);
                t.z = (uint)h[4] | ((uint)h[5] << 16);
                t.w = (uint)h[6] | ((uint)h[7] << 16);
                *reinterpret_cast<uint4*>(&Bh[nxt][cod_b * LDA + dqb]) = t;
                t.x = (uint)l[0] | ((uint)l[1] << 16);
                t.y = (uint)l[2] | ((uint)l[3] << 16);
                t.z = (uint)l[4] | ((uint)l[5] << 16);
                t.w = (uint)l[6] | ((uint)l[7] << 16);
                *reinterpret_cast<uint4*>(&Bl[nxt][cod_b * LDA + dqb]) = t;
            }
        }
        // ---- per-kt epilogue: scores -> running per-lane argmin, reset acc ----
        if ((c & 15) == 15) {
            const int kt = c >> 4;
            const int cd0 = kt * NTT + wn + colk;
            const int cd1 = cd0 + 32;
            const float h0 = hn[cd0];
            const float h1 = hn[cd1];
#pragma unroll
            for (int tm = 0; tm < 2; ++tm) {
#pragma unroll
                for (int r = 0; r < 16; ++r) {
                    float s0 = h0 - acc[tm][0][r];
                    float s1 = h1 - acc[tm][1][r];
                    float v = s0; int cd = cd0;
                    if (s1 < s0) { v = s1; cd = cd1; }   // strict <: smaller code wins ties
                    if (v < bestv[tm][r]) { bestv[tm][r] = v; bestc[tm][r] = cd; }
                    acc[tm][0][r] = 0.f;
                    acc[tm][1][r] = 0.f;
                }
            }
        }
        __syncthreads();   // single barrier per chunk (dbuf)
    }

    // ---- cross-lane argmin: butterfly over the 32 colk lanes ----
#pragma unroll
    for (int tm = 0; tm < 2; ++tm) {
#pragma unroll
        for (int r = 0; r < 16; ++r) {
            float v = bestv[tm][r];
            int cd = bestc[tm][r];
#pragma unroll
            for (int mk = 1; mk < 32; mk <<= 1) {
                float ov = __shfl_xor(v, mk);
                int oc = __shfl_xor(cd, mk);
                if (ov < v || (ov == v && oc < cd)) { v = ov; cd = oc; }
            }
            if (colk == 0) {
                const int row = (r & 3) + 8 * (r >> 2) + 4 * half;  // verified C/D map
                sv[wid >> 1][wm + tm * 32 + row] = v;
                sc[wid >> 1][wm + tm * 32 + row] = cd;
            }
        }
    }
    __syncthreads();
    // ---- combine the 4 n-wave groups ----
    if (tid < MT) {
        float v = sv[0][tid]; int cd = sc[0][tid];
#pragma unroll
        for (int g = 1; g < 4; ++g) {
            float ov = sv[g][tid]; int oc = sc[g][tid];
            if (ov < v || (ov == v && oc < cd)) { v = ov; cd = oc; }
        }
        bc[tid] = cd;
    }
    __syncthreads();
    // ---- fused gather: out[(bq*DD+d)*SS + sb + m] = emb[d*KK + bc[m]] ----
    {
        const int mq = tid & 31;     // float4 group along m
        const int dg = tid >> 5;     // 0..15, 16 d's each
        const int k0 = bc[mq * 4 + 0];
        const int k1 = bc[mq * 4 + 1];
        const int k2 = bc[mq * 4 + 2];
        const int k3 = bc[mq * 4 + 3];
#pragma unroll 4
        for (int dd = 0; dd < 16; ++dd) {
            const int d = dg * 16 + dd;
            const float* er = emb + (size_t)d * KK;
            float4 o = make_float4(er[k0], er[k1], er[k2], er[k3]);
            reinterpret_cast<float4*>(&out[((size_t)bq * DD + d) * SS + sb])[mq] = o;
        }
    }
}

extern "C" void kernel_launch(void* const* d_in, const int* in_sizes, int n_in,
                              void* d_out, int out_size, void* d_ws, size_t ws_size,
                              hipStream_t stream) {
    const float* x = (const float*)d_in[0];     // (32,256,32,32)
    const float* emb = (const float*)d_in[1];   // (256,2048)
    float* out = (float*)d_out;
    float* hn = (float*)d_ws;                   // 2048 f32 = 8 KB (proven safe)
    uint* epk = (uint*)((char*)d_ws + KK * sizeof(float));  // 2 MB packed emb

    const size_t need = (size_t)KK * 4 + (size_t)2 * EPLANE * 4;  // 2.01 MB

    hipLaunchKernelGGL(hn_kernel, dim3(KK / 256), dim3(256), 0, stream, emb, hn);
    if (ws_size >= need) {
        hipLaunchKernelGGL(pack_emb, dim3(EPLANE / 256), dim3(256), 0, stream,
                           emb, epk);
        hipLaunchKernelGGL(pack_x, dim3(4096), dim3(256), 0, stream,
                           x, (uint*)out);
        hipLaunchKernelGGL((vq_fused<true>), dim3(NN / MT), dim3(512), 0, stream,
                           x, emb, hn, epk, out);
    } else {
        hipLaunchKernelGGL((vq_fused<false>), dim3(NN / MT), dim3(512), 0, stream,
                           x, emb, hn, epk, out);
    }
}